// Round 3
// baseline (5164.624 us; speedup 1.0000x reference)
//
#include <hip/hip_runtime.h>

// AdaptiveDownsampling: farthest point sampling (B=8, N=8192, m=4096) + gather.
// Outputs concatenated flat: dp [8,4096,3] then df [8,4096,256], float32.
//
// r2: np reference computes in float64 -> exact path must be fp64.
// r3-r5: register-array spill / AGPR tax lessons; named scalars only.
// r6: fp32 screen + rare exact fp64 path. 5275 us.
// r7: DPP wave max, packed-fp32 screen, precomputed margin. 4239 us.
// r8: FAILED (5264): redundant block reduce in every wave. VALU issue x16.
// r9: dirty-wave caching + fused v_max_u32_dpp ladders. 4198 us.
//     Counters: VALUBusy 2.04->1.56% (active ~50%), dur flat => iteration is
//     half VALU-issue (screen dominates), half sync/LDS-latency stall.
// r10: bucket-FPS. Setup kernel Morton-counting-sorts points (4096 cells,
//     12-bit code) so each thread's 8 points are spatially compact; fps
//     culls per-lane with a conservative sphere test (group min-distance
//     vs thread max mind, fp32 with 1e-5 margins, sound vs fp64 path) and
//     whole waves skip the screen via __any(need). Cached per-wave results
//     (r9) stay valid on skip. Original indices ride through atomicMin
//     packed (oidx<<13 | sorted_pos) for the exact numpy tie-break.

typedef float v2f __attribute__((ext_vector_type(2)));

#define BATCH 8
#define NPTS  8192
#define MSEL  4096
#define NFEAT 256
#define BLOCK 1024
#define NWAVE (BLOCK / 64)

// fp64 square, opaque to the compiler so no v_fma_f64 contraction can merge
// the following adds (numpy float64 does separate mul / add / add).
__device__ __forceinline__ double sqd(double x) {
    double r;
    asm("v_mul_f64 %0, %1, %1" : "=v"(r) : "v"(x));
    return r;
}

// Exact 64-lane u32 max via fused DPP max ops, result wave-uniform in SGPR.
// bound_ctrl:0 => out-of-range DPP sources read 0 (identity for unsigned max).
// Requires full exec / uniform control flow at the call site.
__device__ __forceinline__ unsigned wave_umax_rl(unsigned v) {
    unsigned s;
    asm volatile(
        "s_nop 1\n\t"
        "v_max_u32_dpp %1, %1, %1 row_shr:1  row_mask:0xf bank_mask:0xf bound_ctrl:0\n\t"
        "s_nop 1\n\t"
        "v_max_u32_dpp %1, %1, %1 row_shr:2  row_mask:0xf bank_mask:0xf bound_ctrl:0\n\t"
        "s_nop 1\n\t"
        "v_max_u32_dpp %1, %1, %1 row_shr:4  row_mask:0xf bank_mask:0xf bound_ctrl:0\n\t"
        "s_nop 1\n\t"
        "v_max_u32_dpp %1, %1, %1 row_shr:8  row_mask:0xf bank_mask:0xf bound_ctrl:0\n\t"
        "s_nop 1\n\t"
        "v_max_u32_dpp %1, %1, %1 row_bcast:15 row_mask:0xf bank_mask:0xf bound_ctrl:0\n\t"
        "s_nop 1\n\t"
        "v_max_u32_dpp %1, %1, %1 row_bcast:31 row_mask:0xf bank_mask:0xf bound_ctrl:0\n\t"
        "s_nop 1\n\t"
        "v_readlane_b32 %0, %1, 63"
        : "=s"(s), "+v"(v));
    return s;
}

// ---------------- setup: Morton counting sort (per batch) ----------------

__device__ __forceinline__ unsigned part3_4(unsigned v) {   // 4 bits -> 12
    return (v & 1u) | ((v & 2u) << 2) | ((v & 4u) << 4) | ((v & 8u) << 6);
}

__device__ __forceinline__ unsigned mcode(float x, float y, float z) {
    int qx = (int)((x + 4.f) * 2.f); qx = qx < 0 ? 0 : (qx > 15 ? 15 : qx);
    int qy = (int)((y + 4.f) * 2.f); qy = qy < 0 ? 0 : (qy > 15 ? 15 : qy);
    int qz = (int)((z + 4.f) * 2.f); qz = qz < 0 ? 0 : (qz > 15 ? 15 : qz);
    return part3_4((unsigned)qx) | (part3_4((unsigned)qy) << 1)
         | (part3_4((unsigned)qz) << 2);                    // 12-bit code
}

__launch_bounds__(BLOCK, 1)
__global__ void sort_kernel(const float* __restrict__ pts,       // [B,N,3]
                            float* __restrict__ spts,            // [B,N,3] sorted
                            unsigned short* __restrict__ soidx)  // [B,N] orig idx
{
    __shared__ unsigned s_hist[4096];
    __shared__ unsigned s_part[64];
    const int b = blockIdx.x, tid = threadIdx.x;
    const float* p = pts + (size_t)b * NPTS * 3;
    float* sp = spts + (size_t)b * NPTS * 3;
    unsigned short* so = soidx + (size_t)b * NPTS;

    for (int i = tid; i < 4096; i += BLOCK) s_hist[i] = 0u;
    __syncthreads();

    unsigned code[8];
#pragma unroll
    for (int j = 0; j < 8; ++j) {
        const int i = tid * 8 + j;
        code[j] = mcode(p[i * 3 + 0], p[i * 3 + 1], p[i * 3 + 2]);
        atomicAdd(&s_hist[code[j]], 1u);
    }
    __syncthreads();

    // exclusive prefix sum over 4096 buckets, two-level serial (one-time)
    if (tid < 64) {
        unsigned a = 0;
        for (int k = 0; k < 64; ++k) a += s_hist[tid * 64 + k];
        s_part[tid] = a;
    }
    __syncthreads();
    if (tid == 0) {
        unsigned acc = 0;
        for (int i = 0; i < 64; ++i) { unsigned c = s_part[i]; s_part[i] = acc; acc += c; }
    }
    __syncthreads();
    if (tid < 64) {
        unsigned a = s_part[tid];
        for (int k = 0; k < 64; ++k) {
            unsigned c = s_hist[tid * 64 + k];
            s_hist[tid * 64 + k] = a;       // hist -> running base (scatter bumps it)
            a += c;
        }
    }
    __syncthreads();

#pragma unroll
    for (int j = 0; j < 8; ++j) {
        const int i = tid * 8 + j;
        const unsigned pos = atomicAdd(&s_hist[code[j]], 1u);
        sp[pos * 3 + 0] = p[i * 3 + 0];
        sp[pos * 3 + 1] = p[i * 3 + 1];
        sp[pos * 3 + 2] = p[i * 3 + 2];
        so[pos] = (unsigned short)i;
    }
}

// ---------------- FPS ----------------

__launch_bounds__(BLOCK, 1)
__global__ void fps_kernel(const float* __restrict__ pts,    // [B,N,3] original
                           const float* __restrict__ spts,   // [B,N,3] sorted
                           const unsigned short* __restrict__ soidx, // [B,N]
                           float* __restrict__ dp,           // [B,M,3]
                           int* __restrict__ idx_out)        // [B,M]
{
    __shared__ float s_pts[NPTS * 3];          // 96 KB sorted fp32 copy
    __shared__ unsigned long long s_bmax[2];   // block max, double bits (nonneg)
    __shared__ int s_widx[2];                  // packed (oidx<<13|pos) via atomicMin

    const int b    = blockIdx.x;
    const int tid  = threadIdx.x;
    const int lane = tid & 63;
    const float* p  = pts  + (size_t)b * NPTS * 3;
    const float* sp = spts + (size_t)b * NPTS * 3;
    const unsigned short* so = soidx + (size_t)b * NPTS;

    for (int i = tid; i < NPTS * 3; i += BLOCK) s_pts[i] = sp[i];
    if (tid == 0) {
        s_bmax[0] = 0ull;        s_bmax[1] = 0ull;
        s_widx[0] = 0x7fffffff;  s_widx[1] = 0x7fffffff;
    }

    // Thread's 8 points = sorted positions [base, base+8): spatially compact.
    const int base = ((tid >> 6) << 9) + ((tid & 63) << 3);
    const float4* pb = (const float4*)(sp + (size_t)base * 3);   // 96B aligned
    const float4 f0 = pb[0], f1 = pb[1], f2 = pb[2], f3 = pb[3], f4 = pb[4], f5 = pb[5];
    // point j coords: (3j+c) -> f[(3j+c)/4][(3j+c)%4]; slots pair (2P,2P+1)
    const v2f pxp0 = {f0.x, f0.w}, pyp0 = {f0.y, f1.x}, pzp0 = {f0.z, f1.y};
    const v2f pxp1 = {f1.z, f2.y}, pyp1 = {f1.w, f2.z}, pzp1 = {f2.x, f2.w};
    const v2f pxp2 = {f3.x, f3.w}, pyp2 = {f3.y, f4.x}, pzp2 = {f3.z, f4.y};
    const v2f pxp3 = {f4.z, f5.y}, pyp3 = {f4.w, f5.z}, pzp3 = {f5.x, f5.w};
    const uint4 ov = *(const uint4*)(so + base);    // 8 original u16 indices

    // group centroid + inflated radius (fp32, conservative margins)
    const float tcx = (f0.x + f0.w + f1.z + f2.y + f3.x + f3.w + f4.z + f5.y) * 0.125f;
    const float tcy = (f0.y + f1.x + f1.w + f2.z + f3.y + f4.x + f4.w + f5.z) * 0.125f;
    const float tcz = (f0.z + f1.y + f2.x + f2.w + f3.z + f4.y + f5.x + f5.w) * 0.125f;
    float r2m = 0.f;
#define RAD(PX, PY, PZ) { \
        const float rx = (PX) - tcx, ry = (PY) - tcy, rz = (PZ) - tcz; \
        r2m = fmaxf(r2m, rx * rx + ry * ry + rz * rz); }
    RAD(pxp0.x, pyp0.x, pzp0.x) RAD(pxp0.y, pyp0.y, pzp0.y)
    RAD(pxp1.x, pyp1.x, pzp1.x) RAD(pxp1.y, pyp1.y, pzp1.y)
    RAD(pxp2.x, pyp2.x, pzp2.x) RAD(pxp2.y, pyp2.y, pzp2.y)
    RAD(pxp3.x, pyp3.x, pzp3.x) RAD(pxp3.y, pyp3.y, pzp3.y)
#undef RAD
    const float r_infl = sqrtf(r2m) * 1.00002f + 1e-20f;

    double mind0 = 1e10, mind1 = 1e10, mind2 = 1e10, mind3 = 1e10;
    double mind4 = 1e10, mind5 = 1e10, mind6 = 1e10, mind7 = 1e10;
    float  mfm0 = 1.0001e10f, mfm1 = 1.0001e10f, mfm2 = 1.0001e10f, mfm3 = 1.0001e10f;
    float  mfm4 = 1.0001e10f, mfm5 = 1.0001e10f, mfm6 = 1.0001e10f, mfm7 = 1.0001e10f;

    // Selection 0 is ORIGINAL point 0 (deterministic start).
    float cx = p[0], cy = p[1], cz = p[2];
    if (tid == 0) {
        dp[(size_t)b * MSEL * 3 + 0] = cx;
        dp[(size_t)b * MSEL * 3 + 1] = cy;
        dp[(size_t)b * MSEL * 3 + 2] = cz;
        idx_out[b * MSEL + 0] = 0;
    }

    double   tbv   = 1e300;        // valid upper bound until first reduce
    bool     dirty = true;         // lane updated since last wave reduce
    unsigned whi = 0u, wlo = 0u;   // cached wave max (double bits), SGPR
    unsigned wn  = 0x7fffffffu;    // cached wave min packed idx at max

    __syncthreads();   // s_pts + slot inits visible

    for (int k = 1; k < MSEL; ++k) {
        // --- conservative sphere cull: can any of my 8 points update? ---
        bool need;
        {
            const float ddx = cx - tcx, ddy = cy - tcy, ddz = cz - tcz;
            const float dist2 = ddx * ddx + ddy * ddy + ddz * ddz;
            const double sd = (double)(sqrtf(dist2) * 0.99998f) - (double)r_infl;
            need = !(sd > 0.0 && sd * sd > tbv * 1.000001);
        }

        if (__any(need)) {
            if (need) {
                const v2f cx2 = {cx, cx}, cy2 = {cy, cy}, cz2 = {cz, cz};
#define EX64(PX, PY, PZ, J) { \
                const double ddx = (double)(PX) - (double)cx; \
                const double ddy = (double)(PY) - (double)cy; \
                const double ddz = (double)(PZ) - (double)cz; \
                const double dd  = (sqd(ddx) + sqd(ddy)) + sqd(ddz); \
                if (dd < mind##J) { mind##J = dd; mfm##J = (float)dd * 1.0001f; dirty = true; } }
#define UPDP(P, J0, J1) { \
                const v2f dx = pxp##P - cx2, dy = pyp##P - cy2, dz = pzp##P - cz2; \
                const v2f d  = dx * dx + dy * dy + dz * dz; \
                if (d.x < mfm##J0) EX64(pxp##P.x, pyp##P.x, pzp##P.x, J0) \
                if (d.y < mfm##J1) EX64(pxp##P.y, pyp##P.y, pzp##P.y, J1) }
                UPDP(0, 0, 1) UPDP(1, 2, 3) UPDP(2, 4, 5) UPDP(3, 6, 7)
#undef UPDP
#undef EX64
            }

            // --- wave reduce only if some lane in this wave updated ---
            if (__any(dirty)) {
                const double a0 = fmax(mind0, mind1), a1 = fmax(mind2, mind3);
                const double a2 = fmax(mind4, mind5), a3 = fmax(mind6, mind7);
                tbv = fmax(fmax(a0, a1), fmax(a2, a3));
                dirty = false;

                const unsigned long long tb = (unsigned long long)__double_as_longlong(tbv);
                const unsigned thi = (unsigned)(tb >> 32);
                const unsigned tlo = (unsigned)tb;
                whi = wave_umax_rl(thi);
                wlo = wave_umax_rl(thi == whi ? tlo : 0u);

                // per-wave min packed (oidx<<13|pos) among owners: numpy
                // tie-break = smallest ORIGINAL index (oidx-major min).
                unsigned n = 0x7fffffffu;
                if (thi == whi && tlo == wlo) {
#define OWN(J, OI) if (mind##J == tbv) { \
                    const unsigned cand = ((OI) << 13) | (unsigned)(base + J); \
                    n = cand < n ? cand : n; }
                    OWN(0, ov.x & 0xffffu) OWN(1, ov.x >> 16)
                    OWN(2, ov.y & 0xffffu) OWN(3, ov.y >> 16)
                    OWN(4, ov.z & 0xffffu) OWN(5, ov.z >> 16)
                    OWN(6, ov.w & 0xffffu) OWN(7, ov.w >> 16)
#undef OWN
                }
                wn = ~wave_umax_rl(~n);   // min over owners
            }
        }

        const unsigned long long mybits =
            ((unsigned long long)whi << 32) | (unsigned long long)wlo;
        if (lane == 0) atomicMax(&s_bmax[k & 1], mybits);
        __syncthreads();                                   // barrier A

        const unsigned long long bmaxbits = s_bmax[k & 1];
        if (tid == 0) {   // reset NEXT iter's slots (between barriers A and B)
            s_bmax[(k + 1) & 1] = 0ull;
            s_widx[(k + 1) & 1] = 0x7fffffff;
        }

        // --- owner waves publish cached packed idx (one atomic per wave) ---
        if (lane == 0 && mybits == bmaxbits)
            atomicMin(&s_widx[k & 1], (int)wn);
        __syncthreads();                                   // barrier B

        // --- broadcast winner coords from sorted LDS copy ---
        const int   wpacked = s_widx[k & 1];
        const int   wpos  = wpacked & 0x1fff;
        const float wx = s_pts[wpos * 3 + 0];
        const float wy = s_pts[wpos * 3 + 1];
        const float wz = s_pts[wpos * 3 + 2];
        if (tid == 0) {
            idx_out[b * MSEL + k] = wpacked >> 13;     // original index
            float* o = dp + ((size_t)b * MSEL + k) * 3;
            o[0] = wx; o[1] = wy; o[2] = wz;
        }
        cx = wx; cy = wy; cz = wz;
    }
}

// One wave per selected row; lane i moves one float4 (64 * 16B = 1024B = full row).
__global__ void gather_kernel(const float* __restrict__ feats,  // [B, N, C]
                              const int* __restrict__ idx,      // [B, M]
                              float* __restrict__ df)           // [B, M, C]
{
    const int row  = blockIdx.x * 4 + (threadIdx.x >> 6);  // [0, B*M)
    const int lane = threadIdx.x & 63;
    const int b    = row >> 12;         // MSEL = 4096 rows per batch
    const int src  = idx[row];
    const float4* s = (const float4*)(feats + ((size_t)b * NPTS + src) * NFEAT);
    float4*       d = (float4*)(df + (size_t)row * NFEAT);
    d[lane] = s[lane];
}

extern "C" void kernel_launch(void* const* d_in, const int* in_sizes, int n_in,
                              void* d_out, int out_size, void* d_ws, size_t ws_size,
                              hipStream_t stream)
{
    const float* points   = (const float*)d_in[0];   // [8, 8192, 3]
    const float* features = (const float*)d_in[1];   // [8, 8192, 256]
    float* out = (float*)d_out;
    float* dp  = out;                                // [8, 4096, 3]
    float* df  = out + (size_t)BATCH * MSEL * 3;     // [8, 4096, 256]

    // workspace: idx [128KB] | sorted pts [768KB] | sorted orig idx [128KB]
    int*   idx_ws = (int*)d_ws;
    float* spts   = (float*)((char*)d_ws + 128 * 1024);
    unsigned short* soidx =
        (unsigned short*)((char*)d_ws + 128 * 1024 + BATCH * NPTS * 3 * sizeof(float));

    sort_kernel<<<BATCH, BLOCK, 0, stream>>>(points, spts, soidx);
    fps_kernel<<<BATCH, BLOCK, 0, stream>>>(points, spts, soidx, dp, idx_ws);
    gather_kernel<<<(BATCH * MSEL) / 4, 256, 0, stream>>>(features, idx_ws, df);
}